// Round 1
// baseline (1178.151 us; speedup 1.0000x reference)
//
#include <hip/hip_runtime.h>
#include <math.h>

// Problem constants (fixed by setup_inputs): B=4, C=32, Or=8, H=W=128
#define KOR 5
#define KH 5
#define KW 5
#define OR_ 8
#define H_ 128
#define W_ 128
#define TH 4            // output rows per block
#define LR (TH + 4)     // staged rows  = 8
#define LW (W_ + 4)     // staged cols  = 132
#define NK (KOR*KH*KW)  // 125

__global__ __launch_bounds__(256) void FractionalDilationM2_kernel(
    const float* __restrict__ x,     // [B][C][Or][H][W]
    const float* __restrict__ mp,    // [C][3]
    float* __restrict__ out,         // [B][C][Or][H][W]
    int C)
{
    __shared__ float xs[KOR][LR][LW];   // staged input planes (padded)
    __shared__ float ks[NK];            // morphological kernel for (c,o)

    const int bid  = blockIdx.x;
    const int tile = bid & (H_/TH - 1);     // 0..31
    int rest = bid >> 5;
    const int o = rest & (OR_ - 1);
    rest >>= 3;
    const int c = rest & 31;                // C = 32
    const int b = rest >> 5;

    const int tid = threadIdx.x;

    // ---- per-block morphological kernel values k[c,o,a,j,i] ----
    if (tid < NK) {
        // constants in double to match the numpy reference, then cast
        const double a2d   = 2.0 * 0.65;
        const float  q     = (float)(a2d / (a2d - 1.0));                       // 4.3333...
        const float  coeff = (float)((a2d - 1.0) / a2d * pow(a2d, -1.0 / (a2d - 1.0)));
        const int i = tid % 5;
        const int j = (tid / 5) % 5;
        const int a = tid / 25;

        const float dth  = (float)(0.78539816339744830961 * (double)(a - 2)); // 2pi/8*(a-2)
        const float djv  = (float)(j - 2);
        const float div_ = (float)(i - 2);
        const float th   = (float)(0.78539816339744830961 * (double)o);
        const float cth = cosf(th), sth = sinf(th);
        const float xx =  cth * div_ + sth * djv;
        const float yy = -sth * div_ + cth * djv;
        const float half = dth * 0.5f;
        float cot;
        if (fabsf(half) < 1e-6f) cot = 1.0f;
        else                     cot = half * cosf(half) / sinf(half);
        const float c1 =  cot * xx + half * yy;
        const float c2 = -half * xx + cot * yy;
        const float c3 = dth;
        const float dMain = mp[c*3 + 0];
        const float dLat  = mp[c*3 + 1];
        const float dAng  = mp[c*3 + 2];
        const float t1 = dMain * c1, t2 = dLat * c2, t3 = dAng * c3;
        const float rho = sqrtf(t1*t1 + t2*t2 + t3*t3 + 1e-12f);
        ks[tid] = coeff * powf(rho, q);
    }

    // ---- stage the 5 orientation planes (wrap in Or, -inf spatial pad) ----
    const int h0 = tile * TH;
    const int base_bc = (b * C + c) * (OR_ * H_ * W_);
    for (int idx = tid; idx < KOR * LR * LW; idx += 256) {
        const int p   = idx / (LR * LW);
        const int rem = idx - p * (LR * LW);
        const int r   = rem / LW;
        const int cc  = rem - r * LW;
        const int oo   = (o + p - 2 + OR_) & (OR_ - 1);
        const int h_in = h0 + r - 2;
        const int w_in = cc - 2;
        float v = -INFINITY;
        if ((unsigned)h_in < (unsigned)H_ && (unsigned)w_in < (unsigned)W_)
            v = x[base_bc + oo * (H_ * W_) + h_in * W_ + w_in];
        xs[p][r][cc] = v;
    }
    __syncthreads();

    // ---- 125-tap dilation: each thread does 2 adjacent output rows ----
    const int ty = tid >> 7;        // 0..1
    const int tx = tid & 127;       // 0..127
    const int out_base = base_bc + o * (H_ * W_);

    #pragma unroll
    for (int rr = 0; rr < 2; rr++) {
        const int lr = ty * 2 + rr;                 // local output row 0..3
        float m = -INFINITY;
        #pragma unroll
        for (int a = 0; a < KOR; a++) {
            #pragma unroll
            for (int j = 0; j < KH; j++) {
                const float* row = &xs[a][lr + j][tx];
                const float* kr  = &ks[a * 25 + j * 5];
                const float t0 = row[0] - kr[0];
                const float t1 = row[1] - kr[1];
                const float t2 = row[2] - kr[2];
                const float t3 = row[3] - kr[3];
                const float t4 = row[4] - kr[4];
                m = fmaxf(m, fmaxf(fmaxf(t0, t1), fmaxf(fmaxf(t2, t3), t4)));
            }
        }
        out[out_base + (h0 + lr) * W_ + tx] = m;
    }
}

extern "C" void kernel_launch(void* const* d_in, const int* in_sizes, int n_in,
                              void* d_out, int out_size, void* d_ws, size_t ws_size,
                              hipStream_t stream) {
    const float* x  = (const float*)d_in[0];
    const float* mp = (const float*)d_in[1];
    float* out = (float*)d_out;

    const int C = in_sizes[1] / 3;                       // 32
    const int B = in_sizes[0] / (C * OR_ * H_ * W_);     // 4

    const int nblocks = B * C * OR_ * (H_ / TH);         // 32768
    FractionalDilationM2_kernel<<<nblocks, 256, 0, stream>>>(x, mp, out, C);
}

// Round 2
// 209.553 us; speedup vs baseline: 5.6222x; 5.6222x over previous
//
#include <hip/hip_runtime.h>
#include <math.h>

// Problem constants (fixed by setup_inputs): B=4, C=32, Or=8, H=W=128
#define OR_ 8
#define H_  128
#define W_  128
#define TH  8           // output rows per block
#define LR  (TH + 4)    // 12 staged rows
#define LW  (W_ + 4)    // 132 staged cols; LDS col index = w + 2

__global__ __launch_bounds__(256) void FractionalDilationM2_kernel(
    const float* __restrict__ x,     // [B][C][Or][H][W]
    const float* __restrict__ mp,    // [C][3]
    float* __restrict__ out)         // [B][C][Or][H][W]
{
    __shared__ float xs[5][LR][LW];  // 31680 B
    __shared__ float ks[25][8];      // 800 B  (row = (a*5+j), cols 0..4 used)

    const int bid  = blockIdx.x;
    const int tile = bid & 15;            // H/TH = 16 tiles
    const int o    = (bid >> 4) & 7;
    const int c    = (bid >> 7) & 31;
    const int b    = bid >> 12;
    const int tid  = threadIdx.x;

    // ---- per-block morphological kernel values k[c,o,a,j,i] (same math as ref) ----
    if (tid < 125) {
        const double a2d   = 2.0 * 0.65;
        const float  q     = (float)(a2d / (a2d - 1.0));
        const float  coeff = (float)((a2d - 1.0) / a2d * pow(a2d, -1.0 / (a2d - 1.0)));
        const int i = tid % 5;
        const int j = (tid / 5) % 5;
        const int a = tid / 25;

        const float dth  = (float)(0.78539816339744830961 * (double)(a - 2)); // 2pi/8
        const float djv  = (float)(j - 2);
        const float div_ = (float)(i - 2);
        const float th   = (float)(0.78539816339744830961 * (double)o);
        const float cth = cosf(th), sth = sinf(th);
        const float xx =  cth * div_ + sth * djv;
        const float yy = -sth * div_ + cth * djv;
        const float half = dth * 0.5f;
        float cot;
        if (fabsf(half) < 1e-6f) cot = 1.0f;
        else                     cot = half * cosf(half) / sinf(half);
        const float c1 =  cot * xx + half * yy;
        const float c2 = -half * xx + cot * yy;
        const float c3 = dth;
        const float dMain = mp[c*3 + 0];
        const float dLat  = mp[c*3 + 1];
        const float dAng  = mp[c*3 + 2];
        const float t1 = dMain * c1, t2 = dLat * c2, t3 = dAng * c3;
        const float rho = sqrtf(t1*t1 + t2*t2 + t3*t3 + 1e-12f);
        ks[tid / 5][tid % 5] = coeff * powf(rho, q);
    }

    // ---- stage 5 orientation planes x 12 rows, cols shifted +2 ----
    const int h0      = tile * TH;
    const int base_bc = (b * 32 + c) * (OR_ * H_ * W_);

    for (int idx = tid; idx < 60 * 32; idx += 256) {   // 60 rows x 32 float4 segs
        const int row_id = idx >> 5;
        const int seg    = idx & 31;
        const int p      = row_id / 12;
        const int r      = row_id - p * 12;
        const int oo     = (o + p - 2 + OR_) & 7;
        const int h_in   = h0 + r - 2;
        float4 v;
        if ((unsigned)h_in < (unsigned)H_)
            v = *(const float4*)&x[base_bc + oo * (H_ * W_) + h_in * W_ + seg * 4];
        else
            v = make_float4(-INFINITY, -INFINITY, -INFINITY, -INFINITY);
        float2* d = (float2*)&xs[p][r][2 + seg * 4];   // 8B-aligned
        d[0] = make_float2(v.x, v.y);
        d[1] = make_float2(v.z, v.w);
    }
    if (tid < 240) {                                   // edge cols 0,1,130,131
        const int row_id = tid >> 2;
        const int e      = tid & 3;
        const int p      = row_id / 12;
        const int r      = row_id - p * 12;
        const int col    = (e < 2) ? e : 128 + e;
        xs[p][r][col] = -INFINITY;
    }
    __syncthreads();

    // ---- each thread: 1 output row x 4 output cols, all from aligned b128 reads ----
    const int tx = tid & 31;       // col group
    const int ry = tid >> 5;       // local output row 0..7
    const int w0 = tx * 4;         // output col base; read LDS idx w0..w0+7 (= cols w0-2..w0+5)

    float m0 = -INFINITY, m1 = -INFINITY, m2 = -INFINITY, m3 = -INFINITY;

    #pragma unroll
    for (int a = 0; a < 5; a++) {
        #pragma unroll
        for (int j = 0; j < 5; j++) {
            const float4 lo = *(const float4*)&xs[a][ry + j][w0];       // 16B-aligned
            const float4 hi = *(const float4*)&xs[a][ry + j][w0 + 4];
            const float* kr = ks[a * 5 + j];
            const float k0 = kr[0], k1 = kr[1], k2 = kr[2], k3 = kr[3], k4 = kr[4];
            m0 = fmaxf(m0, fmaxf(fmaxf(lo.x - k0, lo.y - k1),
                                 fmaxf(fmaxf(lo.z - k2, lo.w - k3), hi.x - k4)));
            m1 = fmaxf(m1, fmaxf(fmaxf(lo.y - k0, lo.z - k1),
                                 fmaxf(fmaxf(lo.w - k2, hi.x - k3), hi.y - k4)));
            m2 = fmaxf(m2, fmaxf(fmaxf(lo.z - k0, lo.w - k1),
                                 fmaxf(fmaxf(hi.x - k2, hi.y - k3), hi.z - k4)));
            m3 = fmaxf(m3, fmaxf(fmaxf(lo.w - k0, hi.x - k1),
                                 fmaxf(fmaxf(hi.y - k2, hi.z - k3), hi.w - k4)));
        }
    }

    *(float4*)&out[base_bc + o * (H_ * W_) + (h0 + ry) * W_ + w0] =
        make_float4(m0, m1, m2, m3);
}

extern "C" void kernel_launch(void* const* d_in, const int* in_sizes, int n_in,
                              void* d_out, int out_size, void* d_ws, size_t ws_size,
                              hipStream_t stream) {
    const float* x  = (const float*)d_in[0];
    const float* mp = (const float*)d_in[1];
    float* out = (float*)d_out;

    const int C = in_sizes[1] / 3;                       // 32
    const int B = in_sizes[0] / (C * OR_ * H_ * W_);     // 4

    const int nblocks = B * C * OR_ * (H_ / TH);         // 16384
    FractionalDilationM2_kernel<<<nblocks, 256, 0, stream>>>(x, mp, out);
}